// Round 4
// baseline (1373.150 us; speedup 1.0000x reference)
//
#include <hip/hip_runtime.h>
#include <hip/hip_fp16.h>
#include <stdint.h>

#define S_DIM 64
#define L_DIM 64
#define B_DIM 16
#define LB    1024      // L*B
#define DIN   1024
#define DA    512
#define M_TOT 65536     // S*LB

// fused score GEMM geometry: BM=128, BN=256 (2 partials), BK=64, 3 blocks/CU
#define BM 128
#define BN 256
#define BK 64
#define NT (DIN / BK)   // 16 K-tiles

using f16x8 = __attribute__((ext_vector_type(8))) _Float16;
using f32x4 = __attribute__((ext_vector_type(4))) float;

typedef const __attribute__((address_space(1))) void* gas_ptr;
typedef __attribute__((address_space(3))) void* las_ptr;

__device__ __forceinline__ void load_lds16(const void* g, void* l) {
    __builtin_amdgcn_global_load_lds((gas_ptr)g, (las_ptr)l, 16, 0, 0);
}

__device__ __forceinline__ float fast_tanh(float x) {
    return 1.0f - 2.0f / (__expf(2.0f * x) + 1.0f);
}

// ---------------- K0a: convert Wc, Wq, query to fp16 in workspace ----------
__global__ void cvt_all(const float* __restrict__ Wc, const float* __restrict__ Wq,
                        const float* __restrict__ q,
                        _Float16* __restrict__ Wch, _Float16* __restrict__ Wqh,
                        _Float16* __restrict__ Qh) {
    int i = blockIdx.x * 256 + threadIdx.x;
    if (i < DA * DIN)            Wch[i] = (_Float16)Wc[i];
    else if (i < 2 * DA * DIN)   Wqh[i - DA * DIN] = (_Float16)Wq[i - DA * DIN];
    else                         Qh[i - 2 * DA * DIN] = (_Float16)q[i - 2 * DA * DIN];
}

// ---------------- K0b: qp'[lb][n] = query@Wq^T + bq + bc -------------------
__global__ __launch_bounds__(256) void qp_gemm(
    const _Float16* __restrict__ Qh,    // [LB][DIN]
    const _Float16* __restrict__ Wqh,   // [DA][DIN]
    const float* __restrict__ bq, const float* __restrict__ bc,
    float* __restrict__ qp)             // [LB][DA]
{
    __shared__ __align__(16) _Float16 lA[64 * 64];
    __shared__ __align__(16) _Float16 lB[64 * 64];
    const int t = threadIdx.x;
    const int w = t >> 6, lane = t & 63;
    const int quad = lane >> 4, m16 = lane & 15;
    const int n0 = blockIdx.x * 64, lb0 = blockIdx.y * 64;

    f32x4 acc[4] = {};

    for (int kt = 0; kt < DIN / 64; ++kt) {
#pragma unroll
        for (int i = 0; i < 2; ++i) {
            int c = (w * 2 + i) * 64 + lane;
            int row = c >> 3;
            int kc = (c & 7) ^ (row & 7);
            load_lds16(Qh  + (size_t)(lb0 + row) * DIN + kt * 64 + kc * 8, (char*)lA + (size_t)c * 16);
            load_lds16(Wqh + (size_t)(n0  + row) * DIN + kt * 64 + kc * 8, (char*)lB + (size_t)c * 16);
        }
        __syncthreads();
#pragma unroll
        for (int kk = 0; kk < 64; kk += 32) {
            int cq = (kk >> 3) + quad;
            int ar = 16 * w + m16;
            f16x8 a = *(const f16x8*)((const char*)lA + ar * 128 + ((cq ^ (ar & 7)) * 16));
#pragma unroll
            for (int j = 0; j < 4; ++j) {
                int br = 16 * j + m16;
                f16x8 b = *(const f16x8*)((const char*)lB + br * 128 + ((cq ^ (br & 7)) * 16));
                acc[j] = __builtin_amdgcn_mfma_f32_16x16x32_f16(a, b, acc[j], 0, 0, 0);
            }
        }
        __syncthreads();
    }
#pragma unroll
    for (int j = 0; j < 4; ++j) {
        int n = n0 + 16 * j + m16;
        float bias = bq[n] + bc[n];
#pragma unroll
        for (int r = 0; r < 4; ++r) {
            int lb = lb0 + 16 * w + quad * 4 + r;
            qp[(size_t)lb * DA + n] = acc[j][r] + bias;
        }
    }
}

// ---------------- K1: fused cvt + score GEMM, occupancy-first --------------
// BM=128, BN=256 (nq partial), BK=64, single-buffered LDS (50 KB, 3 blk/CU).
// fp32 ctx read once per nq (nq pair on same XCD -> L2 hit); ctxh written by
// nq==0 blocks only. qp folded into MFMA C-init. Counted vmcnt: stores and
// next-tile A prefetch stay in flight across the barrier.
__global__ __launch_bounds__(512, 6) void score_gemm5(
    const float* __restrict__ ctx,      // [M_TOT][DIN] fp32
    const _Float16* __restrict__ Wch,   // [DA][DIN] fp16 (L2-resident)
    const float* __restrict__ qp,       // [LB][DA]
    const float* __restrict__ v,        // [DA]
    _Float16* __restrict__ ctxh,        // [M_TOT][DIN] fp16 out
    float* __restrict__ sc)             // [2][M_TOT] score partials
{
    __shared__ __align__(16) _Float16 lA[BM * BK];   // 16 KB
    __shared__ __align__(16) _Float16 lB[BN * BK];   // 32 KB
    __shared__ float lP[4][BM];                      // 2 KB  -> 50 KB total

    const int t = threadIdx.x;
    const int w = t >> 6, lane = t & 63;
    const int quad = lane >> 4, m16 = lane & 15;
    const int wm = w & 1, wn = w >> 1;          // 2 M-halves x 4 N-quarters

    // nq pair (bid, bid+8) lands on the same XCD, adjacent in dispatch:
    int bid = blockIdx.x;                 // 1024 blocks
    int xcd = bid & 7;
    int idx = bid >> 3;                   // 0..127 within XCD
    const int nq = idx & 1;
    const int mb = xcd * 64 + (idx >> 1); // 0..511
    const int m0 = mb * BM;
    const int n0 = nq * BN;
    const int lb0 = m0 & (LB - 1);
    const bool wr_ctxh = (nq == 0);

    // ---- A staging geometry: 128 rows x 64 cols fp32, 512 threads ----
    const int arow = t >> 2;              // 0..127
    const int c0   = (t & 3) * 2;         // chunk pair {c0, c0+1} of 8

    // ---- B staging: 256 rows x 8 chunks = 2048 chunks, 4/thread (DMA) ----
    auto stageB = [&](int kt) {
#pragma unroll
        for (int i = 0; i < 4; ++i) {
            int c = (w * 4 + i) * 64 + lane;      // 0..2047
            int row = c >> 3;                     // 0..255
            int kc = (c & 7) ^ (row & 7);
            load_lds16(Wch + (size_t)(n0 + row) * DIN + kt * BK + kc * 8,
                       (char*)lB + (size_t)c * 16);
        }
    };

    f32x4 pf[4];
    auto issueA = [&](int kt) {
        const float* p = ctx + (size_t)(m0 + arow) * DIN + kt * BK + c0 * 8;
        pf[0] = *(const f32x4*)(p);
        pf[1] = *(const f32x4*)(p + 4);
        pf[2] = *(const f32x4*)(p + 8);
        pf[3] = *(const f32x4*)(p + 12);
    };

    issueA(0);

    // qp C-init (vm loads retire under the auto-wait for pf at iter 0)
    f32x4 acc[4][4];
#pragma unroll
    for (int i = 0; i < 4; ++i) {
        int rl = lb0 + wm * 64 + 16 * i + quad * 4;
#pragma unroll
        for (int j = 0; j < 4; ++j) {
            int n = n0 + wn * 64 + 16 * j + m16;
#pragma unroll
            for (int r = 0; r < 4; ++r)
                acc[i][j][r] = qp[(size_t)(rl + r) * DA + n];
        }
    }

    for (int kt = 0; kt < NT; ++kt) {
        stageB(kt);                       // 4 DMA loads into lB (single buffer)

        // cvt the prefetched fp32 A chunk (auto-waits pf of this tile)
        f16x8 h0 = {(_Float16)pf[0][0], (_Float16)pf[0][1], (_Float16)pf[0][2], (_Float16)pf[0][3],
                    (_Float16)pf[1][0], (_Float16)pf[1][1], (_Float16)pf[1][2], (_Float16)pf[1][3]};
        f16x8 h1 = {(_Float16)pf[2][0], (_Float16)pf[2][1], (_Float16)pf[2][2], (_Float16)pf[2][3],
                    (_Float16)pf[3][0], (_Float16)pf[3][1], (_Float16)pf[3][2], (_Float16)pf[3][3]};
        *(f16x8*)((char*)lA + arow * 128 + (((c0)     ^ (arow & 7)) * 16)) = h0;
        *(f16x8*)((char*)lA + arow * 128 + (((c0 + 1) ^ (arow & 7)) * 16)) = h1;
        if (wr_ctxh) {
            _Float16* cd = ctxh + (size_t)(m0 + arow) * DIN + kt * BK + c0 * 8;
            *(f16x8*)cd = h0;
            *(f16x8*)(cd + 8) = h1;
        }

        // prefetch next A tile into regs (stays in flight across barrier)
        issueA(kt + 1 < NT ? kt + 1 : NT - 1);

        // wait only for the 4 B-DMA ops (oldest); stores + A-prefetch fly on
        if (wr_ctxh) asm volatile("s_waitcnt vmcnt(6)" ::: "memory");
        else         asm volatile("s_waitcnt vmcnt(4)" ::: "memory");
        asm volatile("s_waitcnt lgkmcnt(0)" ::: "memory");
        __builtin_amdgcn_s_barrier();
        __builtin_amdgcn_sched_barrier(0);

#pragma unroll
        for (int kk2 = 0; kk2 < 2; ++kk2) {
            int cq = kk2 * 4 + quad;
            f16x8 a[4], b[4];
#pragma unroll
            for (int i = 0; i < 4; ++i) {
                int ar = wm * 64 + 16 * i + m16;
                a[i] = *(const f16x8*)((const char*)lA + ar * 128 + ((cq ^ (ar & 7)) * 16));
            }
#pragma unroll
            for (int j = 0; j < 4; ++j) {
                int br = wn * 64 + 16 * j + m16;
                b[j] = *(const f16x8*)((const char*)lB + br * 128 + ((cq ^ (br & 7)) * 16));
            }
            __builtin_amdgcn_s_setprio(1);
#pragma unroll
            for (int i = 0; i < 4; ++i)
#pragma unroll
                for (int j = 0; j < 4; ++j)
                    acc[i][j] = __builtin_amdgcn_mfma_f32_16x16x32_f16(a[i], b[j], acc[i][j], 0, 0, 0);
            __builtin_amdgcn_s_setprio(0);
        }

        __builtin_amdgcn_sched_barrier(0);
        __builtin_amdgcn_s_barrier();     // reads of this tile done block-wide
        __builtin_amdgcn_sched_barrier(0);
    }

    // epilogue: tanh + v-dot (qp already folded into acc)
    float vv[4];
#pragma unroll
    for (int j = 0; j < 4; ++j) vv[j] = v[n0 + wn * 64 + 16 * j + m16];

    float part[16];
#pragma unroll
    for (int i = 0; i < 4; ++i)
#pragma unroll
        for (int r = 0; r < 4; ++r) {
            float s = 0.f;
#pragma unroll
            for (int j = 0; j < 4; ++j)
                s += fast_tanh(acc[i][j][r]) * vv[j];
            part[i * 4 + r] = s;
        }
#pragma unroll
    for (int off = 1; off < 16; off <<= 1) {
#pragma unroll
        for (int k = 0; k < 16; ++k) part[k] += __shfl_xor(part[k], off, 64);
    }
    if (m16 == 0) {
#pragma unroll
        for (int k = 0; k < 16; ++k) {
            int rl = wm * 64 + 16 * (k >> 2) + quad * 4 + (k & 3);
            lP[wn][rl] = part[k];
        }
    }
    __syncthreads();
    if (t < BM) {
        float s = lP[0][t] + lP[1][t] + lP[2][t] + lP[3][t];
        sc[(size_t)nq * M_TOT + m0 + t] = s;
    }
}

// ---------------- K1-B fallback: fp32-ctx score GEMM (atomic path) ---------
__global__ __launch_bounds__(256, 3) void score_gemm(
    const float* __restrict__ ctx, const _Float16* __restrict__ Wch,
    const float* __restrict__ qp, const float* __restrict__ v,
    float* __restrict__ scores)
{
    __shared__ __align__(16) _Float16 lA[128 * 64];
    __shared__ __align__(16) _Float16 lB[128 * 64];
    __shared__ float lP[2][128];

    const int t = threadIdx.x;
    const int w = t >> 6, lane = t & 63;
    const int quad = lane >> 4, m16 = lane & 15;
    const int wm = w & 1, wn = w >> 1;

    int bid = blockIdx.x;
    int xcd = bid & 7;
    int j2 = bid >> 3;
    int nqf = j2 & 3;
    int mbf = ((j2 >> 2) << 3) | xcd;
    const int m0 = mbf * 128;
    const int n0 = nqf * 128;

    f32x4 acc[4][4] = {};

    const int arow = t >> 1;
    const int akc4 = (t & 1) * 4;
    const float* gA = ctx + (size_t)(m0 + arow) * DIN + (t & 1) * 32;

    for (int kt = 0; kt < DIN / 64; ++kt) {
        {
            const float* p = gA + kt * 64;
            f32x4 f[8];
#pragma unroll
            for (int qd = 0; qd < 8; ++qd) f[qd] = *(const f32x4*)(p + qd * 4);
#pragma unroll
            for (int q2 = 0; q2 < 4; ++q2) {
                f16x8 h = {(_Float16)f[2*q2][0], (_Float16)f[2*q2][1],
                           (_Float16)f[2*q2][2], (_Float16)f[2*q2][3],
                           (_Float16)f[2*q2+1][0], (_Float16)f[2*q2+1][1],
                           (_Float16)f[2*q2+1][2], (_Float16)f[2*q2+1][3]};
                int c = akc4 + q2;
                *(f16x8*)((char*)lA + arow * 128 + ((c ^ (arow & 7)) * 16)) = h;
            }
        }
#pragma unroll
        for (int i = 0; i < 4; ++i) {
            int c = (w * 4 + i) * 64 + lane;
            int row = c >> 3;
            int kc = (c & 7) ^ (row & 7);
            load_lds16(Wch + (size_t)(n0 + row) * DIN + kt * 64 + kc * 8, (char*)lB + (size_t)c * 16);
        }
        __syncthreads();
#pragma unroll
        for (int kk = 0; kk < 64; kk += 32) {
            int cq = (kk >> 3) + quad;
            f16x8 a[4], b[4];
#pragma unroll
            for (int i = 0; i < 4; ++i) {
                int ar = wm * 64 + 16 * i + m16;
                a[i] = *(const f16x8*)((const char*)lA + ar * 128 + ((cq ^ (ar & 7)) * 16));
            }
#pragma unroll
            for (int j = 0; j < 4; ++j) {
                int br = wn * 64 + 16 * j + m16;
                b[j] = *(const f16x8*)((const char*)lB + br * 128 + ((cq ^ (br & 7)) * 16));
            }
#pragma unroll
            for (int i = 0; i < 4; ++i)
#pragma unroll
                for (int j = 0; j < 4; ++j)
                    acc[i][j] = __builtin_amdgcn_mfma_f32_16x16x32_f16(a[i], b[j], acc[i][j], 0, 0, 0);
        }
        __syncthreads();
    }

    float vv[4];
    int nn[4];
#pragma unroll
    for (int j = 0; j < 4; ++j) { nn[j] = n0 + wn * 64 + 16 * j + m16; vv[j] = v[nn[j]]; }

    float part[16];
#pragma unroll
    for (int i = 0; i < 4; ++i) {
#pragma unroll
        for (int r = 0; r < 4; ++r) {
            int gm = m0 + wm * 64 + 16 * i + quad * 4 + r;
            int lb = gm & (LB - 1);
            float s = 0.f;
#pragma unroll
            for (int j = 0; j < 4; ++j) {
                float x = acc[i][j][r] + qp[(size_t)lb * DA + nn[j]];
                s += fast_tanh(x) * vv[j];
            }
            part[i * 4 + r] = s;
        }
    }
#pragma unroll
    for (int off = 1; off < 16; off <<= 1) {
#pragma unroll
        for (int k = 0; k < 16; ++k) part[k] += __shfl_xor(part[k], off, 64);
    }
    if (m16 == 0) {
#pragma unroll
        for (int k = 0; k < 16; ++k) {
            int row_local = wm * 64 + 16 * (k >> 2) + quad * 4 + (k & 3);
            lP[wn][row_local] = part[k];
        }
    }
    __syncthreads();
    if (t < 128) {
        float s = lP[0][t] + lP[1][t];
        atomicAdd(&scores[m0 + t], s);
    }
}

// ---------------- K2: softmax over s — one wave per lb ---------------------
__global__ __launch_bounds__(64) void softmax3(const float* __restrict__ sc,
                                               const int* __restrict__ mask,
                                               float* __restrict__ alpha) {
    int lb = blockIdx.x;
    int s = threadIdx.x;
    int m = s * LB + lb;
    float x = sc[m] + sc[M_TOT + m];
    if (mask[m] == 0) x = -1e9f;
    float mx = x;
#pragma unroll
    for (int off = 1; off < 64; off <<= 1) mx = fmaxf(mx, __shfl_xor(mx, off, 64));
    float e = __expf(x - mx);
    float sum = e;
#pragma unroll
    for (int off = 1; off < 64; off <<= 1) sum += __shfl_xor(sum, off, 64);
    alpha[m] = e / sum;
}

__global__ __launch_bounds__(64) void softmax2(const float* __restrict__ scores,
                                               const int* __restrict__ mask,
                                               float* __restrict__ alpha) {
    int lb = blockIdx.x;
    int s = threadIdx.x;
    float x = scores[s * LB + lb];
    if (mask[s * LB + lb] == 0) x = -1e9f;
    float mx = x;
#pragma unroll
    for (int off = 1; off < 64; off <<= 1) mx = fmaxf(mx, __shfl_xor(mx, off, 64));
    float e = __expf(x - mx);
    float sum = e;
#pragma unroll
    for (int off = 1; off < 64; off <<= 1) sum += __shfl_xor(sum, off, 64);
    alpha[s * LB + lb] = e / sum;
}

// ---------------- K3-A: weighted sum from fp16 ctx_h -----------------------
__global__ __launch_bounds__(128) void weighted_sum2(
    const _Float16* __restrict__ ctxh, const float* __restrict__ alpha,
    float* __restrict__ out) {
    __shared__ float lAl[S_DIM];
    const int lb = blockIdx.x;
    const int t = threadIdx.x;
    if (t < S_DIM) lAl[t] = alpha[t * LB + lb];
    __syncthreads();
    float acc[8] = {};
    const _Float16* base = ctxh + (size_t)lb * DIN + t * 8;
#pragma unroll 8
    for (int s = 0; s < S_DIM; ++s) {
        float a = lAl[s];
        f16x8 c = *(const f16x8*)(base + (size_t)s * LB * DIN);
#pragma unroll
        for (int j = 0; j < 8; ++j) acc[j] += a * (float)c[j];
    }
    f32x4 lo = {acc[0], acc[1], acc[2], acc[3]};
    f32x4 hi = {acc[4], acc[5], acc[6], acc[7]};
    *(f32x4*)(out + (size_t)lb * DIN + t * 8) = lo;
    *(f32x4*)(out + (size_t)lb * DIN + t * 8 + 4) = hi;
}

// ---------------- K3-B fallback: weighted sum from fp32 ctx ----------------
__global__ __launch_bounds__(256) void weighted_sum(
    const float* __restrict__ ctx, const float* __restrict__ alpha,
    float* __restrict__ out) {
    __shared__ float lAl[S_DIM];
    const int lb = blockIdx.x;
    const int t = threadIdx.x;
    if (t < S_DIM) lAl[t] = alpha[t * LB + lb];
    __syncthreads();
    f32x4 acc = {0.f, 0.f, 0.f, 0.f};
    const float* base = ctx + (size_t)lb * DIN + t * 4;
#pragma unroll 4
    for (int s = 0; s < S_DIM; ++s) {
        float a = lAl[s];
        f32x4 c = *(const f32x4*)(base + (size_t)s * LB * DIN);
        acc += a * c;
    }
    *(f32x4*)(out + (size_t)lb * DIN + t * 4) = acc;
}

extern "C" void kernel_launch(void* const* d_in, const int* in_sizes, int n_in,
                              void* d_out, int out_size, void* d_ws, size_t ws_size,
                              hipStream_t stream) {
    (void)in_sizes; (void)n_in; (void)out_size;
    const float* ctx   = (const float*)d_in[0];
    const float* query = (const float*)d_in[1];
    const int*   mask  = (const int*)d_in[2];
    const float* Wc    = (const float*)d_in[3];
    const float* bc    = (const float*)d_in[4];
    const float* Wq    = (const float*)d_in[5];
    const float* bq    = (const float*)d_in[6];
    const float* v     = (const float*)d_in[7];

    float* out_attn  = (float*)d_out;                       // [LB][DIN]
    float* out_alpha = (float*)d_out + (size_t)LB * DIN;    // [S][LB]

    char* ws = (char*)d_ws;
    _Float16* Wch = (_Float16*)(ws);                        // 1 MB
    _Float16* Wqh = (_Float16*)(ws + (1 << 20));            // 1 MB
    _Float16* Qh  = (_Float16*)(ws + (2 << 20));            // 2 MB
    float*    qp  = (float*)(ws + (4 << 20));               // 2 MB
    float*    sc  = (float*)(ws + (6 << 20));               // 512 KB (2 partials)
    _Float16* ctxh = (_Float16*)(ws + (8 << 20));           // 128 MB

    const size_t need = (size_t)(8 + 128) << 20;
    const bool bigws = ws_size >= need;

    cvt_all<<<(2 * DA * DIN + LB * DIN) / 256, 256, 0, stream>>>(Wc, Wq, query, Wch, Wqh, Qh);
    qp_gemm<<<dim3(DA / 64, LB / 64), 256, 0, stream>>>(Qh, Wqh, bq, bc, qp);

    if (bigws) {
        // fused: score GEMM reads fp32 ctx, emits ctxh + score partials
        score_gemm5<<<(M_TOT / BM) * (DA / BN), 512, 0, stream>>>(ctx, Wch, qp, v, ctxh, sc);
        softmax3<<<LB, 64, 0, stream>>>(sc, mask, out_alpha);
        weighted_sum2<<<LB, 128, 0, stream>>>(ctxh, out_alpha, out_attn);
    } else {
        hipMemsetAsync(sc, 0, (size_t)M_TOT * sizeof(float), stream);
        score_gemm<<<2048, 256, 0, stream>>>(ctx, Wch, qp, v, sc);
        softmax2<<<LB, 64, 0, stream>>>(sc, mask, out_alpha);
        weighted_sum<<<LB, 256, 0, stream>>>(ctx, out_alpha, out_attn);
    }
}

// Round 5
// 496.713 us; speedup vs baseline: 2.7645x; 2.7645x over previous
//
#include <hip/hip_runtime.h>
#include <hip/hip_fp16.h>
#include <stdint.h>

#define S_DIM 64
#define L_DIM 64
#define B_DIM 16
#define LB    1024      // L*B
#define DIN   1024
#define DA    512
#define M_TOT 65536     // S*LB

// fused score GEMM geometry: BM=64, BN=256 (2 partials), BK=64, 256 thr,
// ~41 KB LDS + ~135 total regs -> 3 blocks/CU
#define BM 64
#define BN 256
#define BK 64
#define NT (DIN / BK)   // 16 K-tiles

using f16x8 = __attribute__((ext_vector_type(8))) _Float16;
using f32x4 = __attribute__((ext_vector_type(4))) float;

typedef const __attribute__((address_space(1))) void* gas_ptr;
typedef __attribute__((address_space(3))) void* las_ptr;

__device__ __forceinline__ void load_lds16(const void* g, void* l) {
    __builtin_amdgcn_global_load_lds((gas_ptr)g, (las_ptr)l, 16, 0, 0);
}

__device__ __forceinline__ float fast_tanh(float x) {
    return 1.0f - 2.0f / (__expf(2.0f * x) + 1.0f);
}

// ---------------- K0a: convert Wc, Wq, query to fp16 in workspace ----------
__global__ void cvt_all(const float* __restrict__ Wc, const float* __restrict__ Wq,
                        const float* __restrict__ q,
                        _Float16* __restrict__ Wch, _Float16* __restrict__ Wqh,
                        _Float16* __restrict__ Qh) {
    int i = blockIdx.x * 256 + threadIdx.x;
    if (i < DA * DIN)            Wch[i] = (_Float16)Wc[i];
    else if (i < 2 * DA * DIN)   Wqh[i - DA * DIN] = (_Float16)Wq[i - DA * DIN];
    else                         Qh[i - 2 * DA * DIN] = (_Float16)q[i - 2 * DA * DIN];
}

// ---------------- K0b: qp'[lb][n] = query@Wq^T + bq + bc -------------------
__global__ __launch_bounds__(256) void qp_gemm(
    const _Float16* __restrict__ Qh,    // [LB][DIN]
    const _Float16* __restrict__ Wqh,   // [DA][DIN]
    const float* __restrict__ bq, const float* __restrict__ bc,
    float* __restrict__ qp)             // [LB][DA]
{
    __shared__ __align__(16) _Float16 lA[64 * 64];
    __shared__ __align__(16) _Float16 lB[64 * 64];
    const int t = threadIdx.x;
    const int w = t >> 6, lane = t & 63;
    const int quad = lane >> 4, m16 = lane & 15;
    const int n0 = blockIdx.x * 64, lb0 = blockIdx.y * 64;

    f32x4 acc[4] = {};

    for (int kt = 0; kt < DIN / 64; ++kt) {
#pragma unroll
        for (int i = 0; i < 2; ++i) {
            int c = (w * 2 + i) * 64 + lane;
            int row = c >> 3;
            int kc = (c & 7) ^ (row & 7);
            load_lds16(Qh  + (size_t)(lb0 + row) * DIN + kt * 64 + kc * 8, (char*)lA + (size_t)c * 16);
            load_lds16(Wqh + (size_t)(n0  + row) * DIN + kt * 64 + kc * 8, (char*)lB + (size_t)c * 16);
        }
        __syncthreads();
#pragma unroll
        for (int kk = 0; kk < 64; kk += 32) {
            int cq = (kk >> 3) + quad;
            int ar = 16 * w + m16;
            f16x8 a = *(const f16x8*)((const char*)lA + ar * 128 + ((cq ^ (ar & 7)) * 16));
#pragma unroll
            for (int j = 0; j < 4; ++j) {
                int br = 16 * j + m16;
                f16x8 b = *(const f16x8*)((const char*)lB + br * 128 + ((cq ^ (br & 7)) * 16));
                acc[j] = __builtin_amdgcn_mfma_f32_16x16x32_f16(a, b, acc[j], 0, 0, 0);
            }
        }
        __syncthreads();
    }
#pragma unroll
    for (int j = 0; j < 4; ++j) {
        int n = n0 + 16 * j + m16;
        float bias = bq[n] + bc[n];
#pragma unroll
        for (int r = 0; r < 4; ++r) {
            int lb = lb0 + 16 * w + quad * 4 + r;
            qp[(size_t)lb * DA + n] = acc[j][r] + bias;
        }
    }
}

// ---------------- K1: fused cvt + score GEMM, occupancy-first --------------
// 256 threads (4 waves, 1M x 4N), BM=64, BN=256 (nq partial), 41 KB LDS,
// acc[4][4] (64 AGPR) + ~70 VGPR -> 3 waves/SIMD -> 3 blocks/CU.
// fp32 ctx read once per nq (nq pair adjacent on same XCD -> L2 hit);
// ctxh written by nq==0 blocks only. qp folded into MFMA C-init.
// Counted vmcnt: ctxh stores and next-tile A prefetch fly across the barrier.
__global__ __launch_bounds__(256, 3) void score_gemm6(
    const float* __restrict__ ctx,      // [M_TOT][DIN] fp32
    const _Float16* __restrict__ Wch,   // [DA][DIN] fp16 (L2-resident)
    const float* __restrict__ qp,       // [LB][DA]
    const float* __restrict__ v,        // [DA]
    _Float16* __restrict__ ctxh,        // [M_TOT][DIN] fp16 out
    float* __restrict__ sc)             // [2][M_TOT] score partials
{
    __shared__ __align__(16) _Float16 lA[BM * BK];   // 8 KB
    __shared__ __align__(16) _Float16 lB[BN * BK];   // 32 KB
    __shared__ float lP[4][BM];                      // 1 KB  -> 41 KB total

    const int t = threadIdx.x;
    const int w = t >> 6, lane = t & 63;
    const int quad = lane >> 4, m16 = lane & 15;
    const int wn = w;                     // 4 N-quarters, each wave all 64 rows

    // nq pair (bid, bid+8) lands on the same XCD, adjacent in dispatch:
    int bid = blockIdx.x;                 // 2048 blocks
    int xcd = bid & 7;
    int idx = bid >> 3;                   // 0..255 within XCD
    const int nq = idx & 1;
    const int mb = xcd * 128 + (idx >> 1);// 0..1023
    const int m0 = mb * BM;
    const int n0 = nq * BN;
    const int lb0 = m0 & (LB - 1);
    const bool wr_ctxh = (nq == 0);

    // ---- A staging geometry: 64 rows x 64 cols fp32, 256 threads ----
    const int arow = t >> 2;              // 0..63
    const int c0   = (t & 3) * 2;         // chunk pair {c0, c0+1} of 8

    // ---- B staging: 256 rows x 8 chunks = 2048 chunks, 8/thread (DMA) ----
    auto stageB = [&](int kt) {
#pragma unroll
        for (int i = 0; i < 8; ++i) {
            int c = (w * 8 + i) * 64 + lane;      // 0..2047
            int row = c >> 3;                     // 0..255
            int kc = (c & 7) ^ (row & 7);
            load_lds16(Wch + (size_t)(n0 + row) * DIN + kt * BK + kc * 8,
                       (char*)lB + (size_t)c * 16);
        }
    };

    f32x4 pf[4];
    auto issueA = [&](int kt) {
        const float* p = ctx + (size_t)(m0 + arow) * DIN + kt * BK + c0 * 8;
        pf[0] = *(const f32x4*)(p);
        pf[1] = *(const f32x4*)(p + 4);
        pf[2] = *(const f32x4*)(p + 8);
        pf[3] = *(const f32x4*)(p + 12);
    };

    issueA(0);

    // qp C-init (retires under the tile-0 drain)
    f32x4 acc[4][4];
#pragma unroll
    for (int i = 0; i < 4; ++i) {
        int rl = lb0 + 16 * i + quad * 4;
#pragma unroll
        for (int j = 0; j < 4; ++j) {
            int n = n0 + wn * 64 + 16 * j + m16;
#pragma unroll
            for (int r = 0; r < 4; ++r)
                acc[i][j][r] = qp[(size_t)(rl + r) * DA + n];
        }
    }

    for (int kt = 0; kt < NT; ++kt) {
        stageB(kt);                       // 8 DMA loads into lB (single buffer)

        // cvt the prefetched fp32 A chunk (auto-waits pf of this tile)
        f16x8 h0 = {(_Float16)pf[0][0], (_Float16)pf[0][1], (_Float16)pf[0][2], (_Float16)pf[0][3],
                    (_Float16)pf[1][0], (_Float16)pf[1][1], (_Float16)pf[1][2], (_Float16)pf[1][3]};
        f16x8 h1 = {(_Float16)pf[2][0], (_Float16)pf[2][1], (_Float16)pf[2][2], (_Float16)pf[2][3],
                    (_Float16)pf[3][0], (_Float16)pf[3][1], (_Float16)pf[3][2], (_Float16)pf[3][3]};
        *(f16x8*)((char*)lA + arow * 128 + (((c0)     ^ (arow & 7)) * 16)) = h0;
        *(f16x8*)((char*)lA + arow * 128 + (((c0 + 1) ^ (arow & 7)) * 16)) = h1;
        if (wr_ctxh) {
            _Float16* cd = ctxh + (size_t)(m0 + arow) * DIN + kt * BK + c0 * 8;
            *(f16x8*)cd = h0;
            *(f16x8*)(cd + 8) = h1;
        }

        // prefetch next A tile into regs (stays in flight across barrier)
        issueA(kt + 1 < NT ? kt + 1 : NT - 1);

        // wait only for the 8 B-DMA ops; ctxh stores + A-prefetch fly on
        if (wr_ctxh) asm volatile("s_waitcnt vmcnt(6)" ::: "memory");
        else         asm volatile("s_waitcnt vmcnt(4)" ::: "memory");
        asm volatile("s_waitcnt lgkmcnt(0)" ::: "memory");
        __builtin_amdgcn_s_barrier();
        __builtin_amdgcn_sched_barrier(0);

#pragma unroll
        for (int kk2 = 0; kk2 < 2; ++kk2) {
            int cq = kk2 * 4 + quad;
            f16x8 a[4], b[4];
#pragma unroll
            for (int i = 0; i < 4; ++i) {
                int ar = 16 * i + m16;
                a[i] = *(const f16x8*)((const char*)lA + ar * 128 + ((cq ^ (ar & 7)) * 16));
            }
#pragma unroll
            for (int j = 0; j < 4; ++j) {
                int br = wn * 64 + 16 * j + m16;
                b[j] = *(const f16x8*)((const char*)lB + br * 128 + ((cq ^ (br & 7)) * 16));
            }
            __builtin_amdgcn_s_setprio(1);
#pragma unroll
            for (int i = 0; i < 4; ++i)
#pragma unroll
                for (int j = 0; j < 4; ++j)
                    acc[i][j] = __builtin_amdgcn_mfma_f32_16x16x32_f16(a[i], b[j], acc[i][j], 0, 0, 0);
            __builtin_amdgcn_s_setprio(0);
        }

        __builtin_amdgcn_sched_barrier(0);
        __builtin_amdgcn_s_barrier();     // reads of this tile done block-wide
        __builtin_amdgcn_sched_barrier(0);
    }

    // epilogue: tanh + v-dot (qp already folded into acc)
    float vv[4];
#pragma unroll
    for (int j = 0; j < 4; ++j) vv[j] = v[n0 + wn * 64 + 16 * j + m16];

    float part[16];
#pragma unroll
    for (int i = 0; i < 4; ++i)
#pragma unroll
        for (int r = 0; r < 4; ++r) {
            float s = 0.f;
#pragma unroll
            for (int j = 0; j < 4; ++j)
                s += fast_tanh(acc[i][j][r]) * vv[j];
            part[i * 4 + r] = s;
        }
#pragma unroll
    for (int off = 1; off < 16; off <<= 1) {
#pragma unroll
        for (int k = 0; k < 16; ++k) part[k] += __shfl_xor(part[k], off, 64);
    }
    if (m16 == 0) {
#pragma unroll
        for (int k = 0; k < 16; ++k) {
            int rl = 16 * (k >> 2) + quad * 4 + (k & 3);
            lP[wn][rl] = part[k];
        }
    }
    __syncthreads();
    if (t < BM) {
        float s = lP[0][t] + lP[1][t] + lP[2][t] + lP[3][t];
        sc[(size_t)nq * M_TOT + m0 + t] = s;
    }
}

// ---------------- K1-B fallback: fp32-ctx score GEMM (atomic path) ---------
__global__ __launch_bounds__(256, 3) void score_gemm(
    const float* __restrict__ ctx, const _Float16* __restrict__ Wch,
    const float* __restrict__ qp, const float* __restrict__ v,
    float* __restrict__ scores)
{
    __shared__ __align__(16) _Float16 lA[128 * 64];
    __shared__ __align__(16) _Float16 lB[128 * 64];
    __shared__ float lP[2][128];

    const int t = threadIdx.x;
    const int w = t >> 6, lane = t & 63;
    const int quad = lane >> 4, m16 = lane & 15;
    const int wm = w & 1, wn = w >> 1;

    int bid = blockIdx.x;
    int xcd = bid & 7;
    int j2 = bid >> 3;
    int nqf = j2 & 3;
    int mbf = ((j2 >> 2) << 3) | xcd;
    const int m0 = mbf * 128;
    const int n0 = nqf * 128;

    f32x4 acc[4][4] = {};

    const int arow = t >> 1;
    const int akc4 = (t & 1) * 4;
    const float* gA = ctx + (size_t)(m0 + arow) * DIN + (t & 1) * 32;

    for (int kt = 0; kt < DIN / 64; ++kt) {
        {
            const float* p = gA + kt * 64;
            f32x4 f[8];
#pragma unroll
            for (int qd = 0; qd < 8; ++qd) f[qd] = *(const f32x4*)(p + qd * 4);
#pragma unroll
            for (int q2 = 0; q2 < 4; ++q2) {
                f16x8 h = {(_Float16)f[2*q2][0], (_Float16)f[2*q2][1],
                           (_Float16)f[2*q2][2], (_Float16)f[2*q2][3],
                           (_Float16)f[2*q2+1][0], (_Float16)f[2*q2+1][1],
                           (_Float16)f[2*q2+1][2], (_Float16)f[2*q2+1][3]};
                int c = akc4 + q2;
                *(f16x8*)((char*)lA + arow * 128 + ((c ^ (arow & 7)) * 16)) = h;
            }
        }
#pragma unroll
        for (int i = 0; i < 4; ++i) {
            int c = (w * 4 + i) * 64 + lane;
            int row = c >> 3;
            int kc = (c & 7) ^ (row & 7);
            load_lds16(Wch + (size_t)(n0 + row) * DIN + kt * 64 + kc * 8, (char*)lB + (size_t)c * 16);
        }
        __syncthreads();
#pragma unroll
        for (int kk = 0; kk < 64; kk += 32) {
            int cq = (kk >> 3) + quad;
            f16x8 a[4], b[4];
#pragma unroll
            for (int i = 0; i < 4; ++i) {
                int ar = wm * 64 + 16 * i + m16;
                a[i] = *(const f16x8*)((const char*)lA + ar * 128 + ((cq ^ (ar & 7)) * 16));
            }
#pragma unroll
            for (int j = 0; j < 4; ++j) {
                int br = wn * 64 + 16 * j + m16;
                b[j] = *(const f16x8*)((const char*)lB + br * 128 + ((cq ^ (br & 7)) * 16));
            }
#pragma unroll
            for (int i = 0; i < 4; ++i)
#pragma unroll
                for (int j = 0; j < 4; ++j)
                    acc[i][j] = __builtin_amdgcn_mfma_f32_16x16x32_f16(a[i], b[j], acc[i][j], 0, 0, 0);
        }
        __syncthreads();
    }

    float vv[4];
    int nn[4];
#pragma unroll
    for (int j = 0; j < 4; ++j) { nn[j] = n0 + wn * 64 + 16 * j + m16; vv[j] = v[nn[j]]; }

    float part[16];
#pragma unroll
    for (int i = 0; i < 4; ++i) {
#pragma unroll
        for (int r = 0; r < 4; ++r) {
            int gm = m0 + wm * 64 + 16 * i + quad * 4 + r;
            int lb = gm & (LB - 1);
            float s = 0.f;
#pragma unroll
            for (int j = 0; j < 4; ++j) {
                float x = acc[i][j][r] + qp[(size_t)lb * DA + nn[j]];
                s += fast_tanh(x) * vv[j];
            }
            part[i * 4 + r] = s;
        }
    }
#pragma unroll
    for (int off = 1; off < 16; off <<= 1) {
#pragma unroll
        for (int k = 0; k < 16; ++k) part[k] += __shfl_xor(part[k], off, 64);
    }
    if (m16 == 0) {
#pragma unroll
        for (int k = 0; k < 16; ++k) {
            int row_local = wm * 64 + 16 * (k >> 2) + quad * 4 + (k & 3);
            lP[wn][row_local] = part[k];
        }
    }
    __syncthreads();
    if (t < 128) {
        float s = lP[0][t] + lP[1][t];
        atomicAdd(&scores[m0 + t], s);
    }
}

// ---------------- K2: softmax over s — one wave per lb ---------------------
__global__ __launch_bounds__(64) void softmax3(const float* __restrict__ sc,
                                               const int* __restrict__ mask,
                                               float* __restrict__ alpha) {
    int lb = blockIdx.x;
    int s = threadIdx.x;
    int m = s * LB + lb;
    float x = sc[m] + sc[M_TOT + m];
    if (mask[m] == 0) x = -1e9f;
    float mx = x;
#pragma unroll
    for (int off = 1; off < 64; off <<= 1) mx = fmaxf(mx, __shfl_xor(mx, off, 64));
    float e = __expf(x - mx);
    float sum = e;
#pragma unroll
    for (int off = 1; off < 64; off <<= 1) sum += __shfl_xor(sum, off, 64);
    alpha[m] = e / sum;
}

__global__ __launch_bounds__(64) void softmax2(const float* __restrict__ scores,
                                               const int* __restrict__ mask,
                                               float* __restrict__ alpha) {
    int lb = blockIdx.x;
    int s = threadIdx.x;
    float x = scores[s * LB + lb];
    if (mask[s * LB + lb] == 0) x = -1e9f;
    float mx = x;
#pragma unroll
    for (int off = 1; off < 64; off <<= 1) mx = fmaxf(mx, __shfl_xor(mx, off, 64));
    float e = __expf(x - mx);
    float sum = e;
#pragma unroll
    for (int off = 1; off < 64; off <<= 1) sum += __shfl_xor(sum, off, 64);
    alpha[s * LB + lb] = e / sum;
}

// ---------------- K3-A: weighted sum from fp16 ctx_h -----------------------
__global__ __launch_bounds__(128) void weighted_sum2(
    const _Float16* __restrict__ ctxh, const float* __restrict__ alpha,
    float* __restrict__ out) {
    __shared__ float lAl[S_DIM];
    const int lb = blockIdx.x;
    const int t = threadIdx.x;
    if (t < S_DIM) lAl[t] = alpha[t * LB + lb];
    __syncthreads();
    float acc[8] = {};
    const _Float16* base = ctxh + (size_t)lb * DIN + t * 8;
#pragma unroll 8
    for (int s = 0; s < S_DIM; ++s) {
        float a = lAl[s];
        f16x8 c = *(const f16x8*)(base + (size_t)s * LB * DIN);
#pragma unroll
        for (int j = 0; j < 8; ++j) acc[j] += a * (float)c[j];
    }
    f32x4 lo = {acc[0], acc[1], acc[2], acc[3]};
    f32x4 hi = {acc[4], acc[5], acc[6], acc[7]};
    *(f32x4*)(out + (size_t)lb * DIN + t * 8) = lo;
    *(f32x4*)(out + (size_t)lb * DIN + t * 8 + 4) = hi;
}

// ---------------- K3-B fallback: weighted sum from fp32 ctx ----------------
__global__ __launch_bounds__(256) void weighted_sum(
    const float* __restrict__ ctx, const float* __restrict__ alpha,
    float* __restrict__ out) {
    __shared__ float lAl[S_DIM];
    const int lb = blockIdx.x;
    const int t = threadIdx.x;
    if (t < S_DIM) lAl[t] = alpha[t * LB + lb];
    __syncthreads();
    f32x4 acc = {0.f, 0.f, 0.f, 0.f};
    const float* base = ctx + (size_t)lb * DIN + t * 4;
#pragma unroll 4
    for (int s = 0; s < S_DIM; ++s) {
        float a = lAl[s];
        f32x4 c = *(const f32x4*)(base + (size_t)s * LB * DIN);
        acc += a * c;
    }
    *(f32x4*)(out + (size_t)lb * DIN + t * 4) = acc;
}

extern "C" void kernel_launch(void* const* d_in, const int* in_sizes, int n_in,
                              void* d_out, int out_size, void* d_ws, size_t ws_size,
                              hipStream_t stream) {
    (void)in_sizes; (void)n_in; (void)out_size;
    const float* ctx   = (const float*)d_in[0];
    const float* query = (const float*)d_in[1];
    const int*   mask  = (const int*)d_in[2];
    const float* Wc    = (const float*)d_in[3];
    const float* bc    = (const float*)d_in[4];
    const float* Wq    = (const float*)d_in[5];
    const float* bq    = (const float*)d_in[6];
    const float* v     = (const float*)d_in[7];

    float* out_attn  = (float*)d_out;                       // [LB][DIN]
    float* out_alpha = (float*)d_out + (size_t)LB * DIN;    // [S][LB]

    char* ws = (char*)d_ws;
    _Float16* Wch = (_Float16*)(ws);                        // 1 MB
    _Float16* Wqh = (_Float16*)(ws + (1 << 20));            // 1 MB
    _Float16* Qh  = (_Float16*)(ws + (2 << 20));            // 2 MB
    float*    qp  = (float*)(ws + (4 << 20));               // 2 MB
    float*    sc  = (float*)(ws + (6 << 20));               // 512 KB (2 partials)
    _Float16* ctxh = (_Float16*)(ws + (8 << 20));           // 128 MB

    const size_t need = (size_t)(8 + 128) << 20;
    const bool bigws = ws_size >= need;

    cvt_all<<<(2 * DA * DIN + LB * DIN) / 256, 256, 0, stream>>>(Wc, Wq, query, Wch, Wqh, Qh);
    qp_gemm<<<dim3(DA / 64, LB / 64), 256, 0, stream>>>(Qh, Wqh, bq, bc, qp);

    if (bigws) {
        // fused: score GEMM reads fp32 ctx, emits ctxh + score partials
        score_gemm6<<<(M_TOT / BM) * (DA / BN), 256, 0, stream>>>(ctx, Wch, qp, v, ctxh, sc);
        softmax3<<<LB, 64, 0, stream>>>(sc, mask, out_alpha);
        weighted_sum2<<<LB, 128, 0, stream>>>(ctxh, out_alpha, out_attn);
    } else {
        hipMemsetAsync(sc, 0, (size_t)M_TOT * sizeof(float), stream);
        score_gemm<<<2048, 256, 0, stream>>>(ctx, Wch, qp, v, sc);
        softmax2<<<LB, 64, 0, stream>>>(sc, mask, out_alpha);
        weighted_sum<<<LB, 256, 0, stream>>>(ctx, out_alpha, out_attn);
    }
}